// Round 11
// baseline (521.265 us; speedup 1.0000x reference)
//
#include <hip/hip_runtime.h>
#include <hip/hip_bf16.h>
#include <cmath>
#include <cstdint>

#define N_TOK 16384
#define DIM   512
#define HID   2048
#define NEXP  4
#define MAX_WL 260   // sum_e ceil(cnt_e/128) <= 2*N_TOK/128 + NEXP

typedef __attribute__((ext_vector_type(8))) short bf16x8;
typedef __attribute__((ext_vector_type(4))) float f32x4;

__device__ __forceinline__ short f2bf(float f) {
  __hip_bfloat16 h = __float2bfloat16(f);
  return *reinterpret_cast<short*>(&h);
}

// gelu_gpt2(x) = 0.5x(1+tanh(c(x+0.044715x^3))) == x * sigmoid(2c(x+0.044715x^3))
__device__ __forceinline__ float gelu_f(float v) {
  float v2 = v * v;
  float u = v * (1.5957691216057308f + 0.07135481283254937f * v2);
  return v / (1.0f + __expf(-u));
}

__device__ __forceinline__ void load_lds16(const void* g, void* l) {
  __builtin_amdgcn_global_load_lds(
      (const __attribute__((address_space(1))) void*)g,
      (__attribute__((address_space(3))) void*)l, 16, 0, 0);
}

// swizzled LDS short-index for a (row, col16) fragment read.
#define LDSIDX(r, c16) (((r) * 64) + ((((c16) ^ ((r) & 7)) * 8)))

// ---------------- convert fp32 -> bf16 (vectorized x4) ----------------
__global__ void cvt_kernel(const float* __restrict__ src, short* __restrict__ dst, int n4) {
  int i = blockIdx.x * blockDim.x + threadIdx.x;
  int stride = gridDim.x * blockDim.x;
  for (; i < n4; i += stride) {
    float4 v = reinterpret_cast<const float4*>(src)[i];
    short4 o;
    o.x = f2bf(v.x); o.y = f2bf(v.y); o.z = f2bf(v.z); o.w = f2bf(v.w);
    reinterpret_cast<short4*>(dst)[i] = o;
  }
}

// ---------------- gate ----------------
__global__ __launch_bounds__(256) void gate_kernel(
    const float* __restrict__ x, const float* __restrict__ gw,
    float* __restrict__ cw, float* __restrict__ gate_sum,
    short* __restrict__ xb) {
  int t = threadIdx.x, wid = t >> 6, lane = t & 63;

  float4 g[NEXP][2];
#pragma unroll
  for (int e = 0; e < NEXP; ++e) {
    const float4* gp = reinterpret_cast<const float4*>(gw + e * DIM + lane * 8);
    g[e][0] = gp[0]; g[e][1] = gp[1];
  }

  float lsum = 0.0f;
  int n0 = blockIdx.x * 64 + wid * 16;
  for (int i = 0; i < 16; ++i) {
    int n = n0 + i;
    const float4* xr4 = reinterpret_cast<const float4*>(x + (size_t)n * DIM);
    float4 a = xr4[lane * 2];
    float4 b = xr4[lane * 2 + 1];

    short4 s0, s1;
    s0.x = f2bf(a.x); s0.y = f2bf(a.y); s0.z = f2bf(a.z); s0.w = f2bf(a.w);
    s1.x = f2bf(b.x); s1.y = f2bf(b.y); s1.z = f2bf(b.z); s1.w = f2bf(b.w);
    short4* xbp = reinterpret_cast<short4*>(xb + (size_t)n * DIM + lane * 8);
    xbp[0] = s0; xbp[1] = s1;

    float p[NEXP];
#pragma unroll
    for (int e = 0; e < NEXP; ++e) {
      p[e] = a.x * g[e][0].x + a.y * g[e][0].y + a.z * g[e][0].z + a.w * g[e][0].w
           + b.x * g[e][1].x + b.y * g[e][1].y + b.z * g[e][1].z + b.w * g[e][1].w;
    }
#pragma unroll
    for (int e = 0; e < NEXP; ++e)
#pragma unroll
      for (int off = 32; off; off >>= 1) p[e] += __shfl_xor(p[e], off);

    if (lane == 0) {
      lsum += p[0] + p[1] + p[2] + p[3];
      int i0 = 0;
#pragma unroll
      for (int e = 1; e < NEXP; ++e) if (p[e] > p[i0]) i0 = e;
      int i1 = -1;
#pragma unroll
      for (int e = 0; e < NEXP; ++e) {
        if (e == i0) continue;
        if (i1 < 0 || p[e] > p[i1]) i1 = e;
      }
      float eb = expf(p[i1] - p[i0]);
      float w0 = 1.0f / (1.0f + eb);
      float w1 = eb / (1.0f + eb);
      float row[NEXP] = {0.f, 0.f, 0.f, 0.f};
      row[i0] = w0; row[i1] = w1;
#pragma unroll
      for (int e = 0; e < NEXP; ++e) cw[n * NEXP + e] = row[e];
    }
  }
  __shared__ float bs[4];
  if (lane == 0) bs[wid] = lsum;
  __syncthreads();
  if (t == 0) atomicAdd(gate_sum, bs[0] + bs[1] + bs[2] + bs[3]);
}

__global__ void loss_kernel(const float* __restrict__ gate_sum, float* __restrict__ out_loss) {
  float m = gate_sum[0] / (float)(N_TOK * NEXP);
  out_loss[0] = m * logf(m + 0.1f);
}

// ---------------- compaction ----------------
__global__ __launch_bounds__(256) void count_kernel(const float* __restrict__ cw,
                                                    int* __restrict__ blockcnt) {
  __shared__ int c[4];
  int t = threadIdx.x;
  if (t < 4) c[t] = 0;
  __syncthreads();
  int n = blockIdx.x * 256 + t;
  float4 w = reinterpret_cast<const float4*>(cw)[n];
  unsigned long long m0 = __ballot(w.x != 0.f);
  unsigned long long m1 = __ballot(w.y != 0.f);
  unsigned long long m2 = __ballot(w.z != 0.f);
  unsigned long long m3 = __ballot(w.w != 0.f);
  if ((t & 63) == 0) {
    atomicAdd(&c[0], (int)__popcll(m0));
    atomicAdd(&c[1], (int)__popcll(m1));
    atomicAdd(&c[2], (int)__popcll(m2));
    atomicAdd(&c[3], (int)__popcll(m3));
  }
  __syncthreads();
  if (t < 4) blockcnt[blockIdx.x * 4 + t] = c[t];
}

// scan + build live-work-list of (expert, bm) row-tiles
__global__ void scan_kernel(const int* __restrict__ blockcnt, int* __restrict__ blockoff,
                            int* __restrict__ counts, int* __restrict__ expbase,
                            int* __restrict__ wl, int* __restrict__ wl_n) {
  int lane = threadIdx.x;  // 64
  int tot[NEXP];
#pragma unroll
  for (int e = 0; e < NEXP; ++e) {
    int v = blockcnt[lane * 4 + e];
    int inc = v;
#pragma unroll
    for (int off = 1; off < 64; off <<= 1) {
      int u = __shfl_up(inc, off);
      if (lane >= off) inc += u;
    }
    blockoff[lane * 4 + e] = inc - v;
    tot[e] = __shfl(inc, 63);
  }
  if (lane == 0) {
    int base = 0;
#pragma unroll
    for (int e = 0; e < NEXP; ++e) {
      counts[e] = tot[e];
      expbase[e] = base;
      base += tot[e];
    }
    int n = 0;
    for (int e = 0; e < NEXP; ++e) {
      int nb = (tot[e] + 127) >> 7;
      for (int b = 0; b < nb; ++b) wl[n++] = (e << 20) | b;
    }
    wl_n[0] = n;
  }
}

__global__ __launch_bounds__(256) void write_kernel(const float* __restrict__ cw,
                                                    const int* __restrict__ blockoff,
                                                    const int* __restrict__ expbase,
                                                    int* __restrict__ list) {
  int t = threadIdx.x, wave = t >> 6, lane = t & 63;
  int blk = blockIdx.x;
  int n = blk * 256 + t;
  float4 w4 = reinterpret_cast<const float4*>(cw)[n];
  float wf[4] = {w4.x, w4.y, w4.z, w4.w};
  __shared__ int wcnt[4][4];
  unsigned long long lt = (1ULL << lane) - 1ULL;
  int pfx[4]; bool sel[4];
#pragma unroll
  for (int e = 0; e < NEXP; ++e) {
    sel[e] = (wf[e] != 0.f);
    unsigned long long m = __ballot(sel[e]);
    pfx[e] = (int)__popcll(m & lt);
    if (lane == 0) wcnt[wave][e] = (int)__popcll(m);
  }
  __syncthreads();
#pragma unroll
  for (int e = 0; e < NEXP; ++e) {
    if (sel[e]) {
      int woff = 0;
      for (int w2 = 0; w2 < wave; ++w2) woff += wcnt[w2][e];
      list[expbase[e] + blockoff[blk * 4 + e] + woff + pfx[e]] = n;
    }
  }
}

// ---------------- routed GEMM1: worklist + XCD swizzle + 2-phase dbuf pipeline ----
__global__ __launch_bounds__(256) void moe_gemm1(
    const short* __restrict__ xb, const short* __restrict__ w1b,
    const float* __restrict__ b1, short* __restrict__ Hc,
    const int* __restrict__ list, const int* __restrict__ counts,
    const int* __restrict__ expbase, const int* __restrict__ wl,
    const int* __restrict__ wl_n) {
  int lg = ((blockIdx.x & 7) * (MAX_WL * 2)) + (blockIdx.x >> 3); // cpx = 4160/8 = 520
  int bn = lg & 15, widx = lg >> 4;
  if (widx >= wl_n[0]) return;
  int entry = wl[widx];
  int e = entry >> 20, bm = entry & 0xFFFFF;
  int cnt = counts[e];
  int base = expbase[e];
  int bm0 = bm * 128;
  int bn0 = bn * 128;
  const short* Bw = w1b + (size_t)e * HID * DIM;

  int t = threadIdx.x, lane = t & 63, wid = t >> 6;
  int srow = t >> 3;
  int scol = ((t & 7) ^ (srow & 7)) * 8;   // pre-swizzled global source column
  const short* Ag[4];
#pragma unroll
  for (int i = 0; i < 4; ++i) {
    int rc = bm0 + i * 32 + srow;
    int tok = list[base + ((rc < cnt) ? rc : 0)];
    Ag[i] = xb + (size_t)tok * DIM + scol;
  }
  const short* Bg = Bw + (size_t)(bn0 + srow) * DIM + scol;

  __shared__ __align__(16) short As[2][128 * 64];
  __shared__ __align__(16) short Bs[2][128 * 64];
  f32x4 acc[4][4] = {};
  int wr = (wid >> 1) * 64, wc = (wid & 1) * 64;
  constexpr int NT = DIM / 64;  // 8

  // prologue: stage tile 0 into buf 0
#pragma unroll
  for (int i = 0; i < 4; ++i) {
    load_lds16(Ag[i], As[0] + i * 2048 + t * 8);
    load_lds16(Bg + (size_t)(i * 32) * DIM, Bs[0] + i * 2048 + t * 8);
  }
  __syncthreads();

  int cur = 0;
  for (int kt = 0; kt < NT; ++kt) {
    // issue next tile into the other buffer BEFORE computing current
    if (kt + 1 < NT) {
      int k0n = (kt + 1) * 64;
#pragma unroll
      for (int i = 0; i < 4; ++i) {
        load_lds16(Ag[i] + k0n, As[cur ^ 1] + i * 2048 + t * 8);
        load_lds16(Bg + (size_t)(i * 32) * DIM + k0n, Bs[cur ^ 1] + i * 2048 + t * 8);
      }
    }
    const short* Asb = As[cur];
    const short* Bsb = Bs[cur];
#pragma unroll
    for (int ks = 0; ks < 2; ++ks) {
      bf16x8 af[4], bfr[4];
#pragma unroll
      for (int mi = 0; mi < 4; ++mi) {
        int r = wr + mi * 16 + (lane & 15);
        af[mi] = *(const bf16x8*)&Asb[LDSIDX(r, ks * 4 + (lane >> 4))];
      }
#pragma unroll
      for (int ni = 0; ni < 4; ++ni) {
        int r = wc + ni * 16 + (lane & 15);
        bfr[ni] = *(const bf16x8*)&Bsb[LDSIDX(r, ks * 4 + (lane >> 4))];
      }
#pragma unroll
      for (int mi = 0; mi < 4; ++mi)
#pragma unroll
        for (int ni = 0; ni < 4; ++ni)
          acc[mi][ni] = __builtin_amdgcn_mfma_f32_16x16x32_bf16(af[mi], bfr[ni], acc[mi][ni], 0, 0, 0);
    }
    __syncthreads();   // drains next-tile loads (issued above) + protects buffer reuse
    cur ^= 1;
  }

  int crow = (lane >> 4) * 4, ccol = lane & 15;
#pragma unroll
  for (int mi = 0; mi < 4; ++mi) {
#pragma unroll
    for (int ni = 0; ni < 4; ++ni) {
      int col = bn0 + wc + ni * 16 + ccol;
      float bv = b1[(size_t)e * HID + col];
#pragma unroll
      for (int j = 0; j < 4; ++j) {
        int rc = bm0 + wr + mi * 16 + crow + j;
        if (rc < cnt)
          Hc[(size_t)(base + rc) * HID + col] = f2bf(gelu_f(acc[mi][ni][j] + bv));
      }
    }
  }
}

// ---------------- routed GEMM2: worklist + XCD swizzle + 2-phase dbuf, atomic epilogue ----
__global__ __launch_bounds__(256) void moe_gemm2(
    const short* __restrict__ Hc, const short* __restrict__ w2b,
    const float* __restrict__ b2, float* __restrict__ out,
    const float* __restrict__ cw, const int* __restrict__ list,
    const int* __restrict__ counts, const int* __restrict__ expbase,
    const int* __restrict__ wl, const int* __restrict__ wl_n) {
  int lg = ((blockIdx.x & 7) * (MAX_WL / 2)) + (blockIdx.x >> 3); // cpx = 1040/8 = 130
  int bn = lg & 3, widx = lg >> 2;
  if (widx >= wl_n[0]) return;
  int entry = wl[widx];
  int e = entry >> 20, bm = entry & 0xFFFFF;
  int cnt = counts[e];
  int base = expbase[e];
  int bm0 = bm * 128;
  int bn0 = bn * 128;
  const short* Bw = w2b + (size_t)e * DIM * HID;

  int t = threadIdx.x, lane = t & 63, wid = t >> 6;
  int srow = t >> 3;
  int scol = ((t & 7) ^ (srow & 7)) * 8;
  const short* Ag = Hc + (size_t)(base + bm0 + srow) * HID + scol;
  const short* Bg = Bw + (size_t)(bn0 + srow) * HID + scol;

  __shared__ __align__(16) short As[2][128 * 64];
  __shared__ __align__(16) short Bs[2][128 * 64];
  f32x4 acc[4][4] = {};
  int wr = (wid >> 1) * 64, wc = (wid & 1) * 64;
  constexpr int NT = HID / 64;  // 32

  // prologue
#pragma unroll
  for (int i = 0; i < 4; ++i) {
    load_lds16(Ag + (size_t)(i * 32) * HID, As[0] + i * 2048 + t * 8);
    load_lds16(Bg + (size_t)(i * 32) * HID, Bs[0] + i * 2048 + t * 8);
  }
  __syncthreads();

  int cur = 0;
  for (int kt = 0; kt < NT; ++kt) {
    if (kt + 1 < NT) {
      int k0n = (kt + 1) * 64;
#pragma unroll
      for (int i = 0; i < 4; ++i) {
        load_lds16(Ag + (size_t)(i * 32) * HID + k0n, As[cur ^ 1] + i * 2048 + t * 8);
        load_lds16(Bg + (size_t)(i * 32) * HID + k0n, Bs[cur ^ 1] + i * 2048 + t * 8);
      }
    }
    const short* Asb = As[cur];
    const short* Bsb = Bs[cur];
#pragma unroll
    for (int ks = 0; ks < 2; ++ks) {
      bf16x8 af[4], bfr[4];
#pragma unroll
      for (int mi = 0; mi < 4; ++mi) {
        int r = wr + mi * 16 + (lane & 15);
        af[mi] = *(const bf16x8*)&Asb[LDSIDX(r, ks * 4 + (lane >> 4))];
      }
#pragma unroll
      for (int ni = 0; ni < 4; ++ni) {
        int r = wc + ni * 16 + (lane & 15);
        bfr[ni] = *(const bf16x8*)&Bsb[LDSIDX(r, ks * 4 + (lane >> 4))];
      }
#pragma unroll
      for (int mi = 0; mi < 4; ++mi)
#pragma unroll
        for (int ni = 0; ni < 4; ++ni)
          acc[mi][ni] = __builtin_amdgcn_mfma_f32_16x16x32_bf16(af[mi], bfr[ni], acc[mi][ni], 0, 0, 0);
    }
    __syncthreads();
    cur ^= 1;
  }

  int crow = (lane >> 4) * 4, ccol = lane & 15;
#pragma unroll
  for (int mi = 0; mi < 4; ++mi) {
    int tokr[4]; float wgtr[4]; bool val[4];
#pragma unroll
    for (int j = 0; j < 4; ++j) {
      int rc = bm0 + wr + mi * 16 + crow + j;
      val[j] = (rc < cnt);
      int tok = list[base + (val[j] ? rc : 0)];
      tokr[j] = tok;
      wgtr[j] = cw[tok * NEXP + e];
    }
#pragma unroll
    for (int ni = 0; ni < 4; ++ni) {
      int col = bn0 + wc + ni * 16 + ccol;
      float bv = b2[(size_t)e * DIM + col];
#pragma unroll
      for (int j = 0; j < 4; ++j) {
        if (val[j])
          atomicAdd(&out[(size_t)tokr[j] * DIM + col], wgtr[j] * (acc[mi][ni][j] + bv));
      }
    }
  }
}

// ---------------- dense fallback GEMM ----------------
template <int KDIM, int EPI>
__global__ __launch_bounds__(256) void gemm_kernel(
    const short* __restrict__ A, const short* __restrict__ B,
    const float* __restrict__ bias,
    short* __restrict__ Hout, float* __restrict__ out,
    const float* __restrict__ cw, int expert) {
  constexpr int BK = 64;
  __shared__ __align__(16) short As[128 * BK];
  __shared__ __align__(16) short Bs[128 * BK];
  int t = threadIdx.x;
  int lane = t & 63, wid = t >> 6;
  int bn0 = blockIdx.x * 128;
  int bm0 = blockIdx.y * 128;
  int wr = (wid >> 1) * 64;
  int wc = (wid & 1) * 64;
  f32x4 acc[4][4] = {};
  int srow = t >> 3;
  int scol = (t & 7) * 8;
  const short* Ag = A + (size_t)(bm0 + srow) * KDIM + scol;
  const short* Bg = B + (size_t)(bn0 + srow) * KDIM + scol;
  for (int kt = 0; kt < KDIM / BK; ++kt) {
    if (kt) __syncthreads();
    int k0 = kt * BK;
#pragma unroll
    for (int i = 0; i < 4; ++i) {
      load_lds16(Ag + (size_t)(i * 32) * KDIM + k0, As + i * 2048 + t * 8);
      load_lds16(Bg + (size_t)(i * 32) * KDIM + k0, Bs + i * 2048 + t * 8);
    }
    __syncthreads();
#pragma unroll
    for (int ks = 0; ks < 2; ++ks) {
      int koff = ks * 32 + ((lane >> 4) << 3);
      bf16x8 af[4], bfr[4];
#pragma unroll
      for (int mi = 0; mi < 4; ++mi)
        af[mi] = *(const bf16x8*)&As[(wr + mi * 16 + (lane & 15)) * BK + koff];
#pragma unroll
      for (int ni = 0; ni < 4; ++ni)
        bfr[ni] = *(const bf16x8*)&Bs[(wc + ni * 16 + (lane & 15)) * BK + koff];
#pragma unroll
      for (int mi = 0; mi < 4; ++mi)
#pragma unroll
        for (int ni = 0; ni < 4; ++ni)
          acc[mi][ni] = __builtin_amdgcn_mfma_f32_16x16x32_bf16(af[mi], bfr[ni], acc[mi][ni], 0, 0, 0);
    }
  }
  int crow = (lane >> 4) * 4;
  int ccol = lane & 15;
#pragma unroll
  for (int mi = 0; mi < 4; ++mi) {
#pragma unroll
    for (int ni = 0; ni < 4; ++ni) {
      int col = bn0 + wc + ni * 16 + ccol;
      float bv = bias[col];
#pragma unroll
      for (int j = 0; j < 4; ++j) {
        int row = bm0 + wr + mi * 16 + crow + j;
        float v = acc[mi][ni][j] + bv;
        if constexpr (EPI == 0) {
          Hout[(size_t)row * HID + col] = f2bf(gelu_f(v));
        } else {
          float w = cw[row * NEXP + expert];
          float r = w * v;
          if constexpr (EPI == 1) out[(size_t)row * DIM + col] = r;
          else                    out[(size_t)row * DIM + col] += r;
        }
      }
    }
  }
}

extern "C" void kernel_launch(void* const* d_in, const int* in_sizes, int n_in,
                              void* d_out, int out_size, void* d_ws, size_t ws_size,
                              hipStream_t stream) {
  const float* x  = (const float*)d_in[0];
  const float* gw = (const float*)d_in[1];
  const float* w1 = (const float*)d_in[2];
  const float* b1 = (const float*)d_in[3];
  const float* w2 = (const float*)d_in[4];
  const float* b2 = (const float*)d_in[5];
  float* out = (float*)d_out;

  char* ws = (char*)d_ws;
  float* cw       = (float*)(ws + 0);            // 262144 B
  float* gate_sum = (float*)(ws + 262144);       // 4 B (pad)
  int*   blockcnt = (int*)(ws + 262400);         // 1024 B
  int*   blockoff = (int*)(ws + 263424);         // 1024 B
  int*   counts   = (int*)(ws + 264448);         // 64 B
  int*   expbase  = (int*)(ws + 264512);         // 64 B
  int*   wl_n     = (int*)(ws + 264576);         // 64 B
  int*   wl       = (int*)(ws + 264640);         // 1536 B
  int*   list     = (int*)(ws + 266176);         // 131072 B -> ends 397248
  short* xb       = (short*)(ws + 397248);       // 16 MB -> ends 17174464
  short* w1b      = (short*)(ws + 17174464);     // 8 MB  -> ends 25563072
  short* w2b      = (short*)(ws + 25563072);     // 8 MB  -> ends 33951680
  short* Hc       = (short*)(ws + 33951680);     // (32768+128)*2048*2 B
  const size_t ROUTED_NEED = 33951680ull + (size_t)(32768 + 128) * HID * 2;

  hipMemsetAsync(gate_sum, 0, sizeof(float), stream);
  cvt_kernel<<<1024, 256, 0, stream>>>(w1, w1b, NEXP * HID * DIM / 4);
  cvt_kernel<<<1024, 256, 0, stream>>>(w2, w2b, NEXP * DIM * HID / 4);
  gate_kernel<<<N_TOK / 64, 256, 0, stream>>>(x, gw, cw, gate_sum, xb);
  loss_kernel<<<1, 1, 0, stream>>>(gate_sum, out + (size_t)N_TOK * DIM);

  if (ws_size >= ROUTED_NEED) {
    hipMemsetAsync(out, 0, (size_t)N_TOK * DIM * sizeof(float), stream);
    count_kernel<<<64, 256, 0, stream>>>(cw, blockcnt);
    scan_kernel<<<1, 64, 0, stream>>>(blockcnt, blockoff, counts, expbase, wl, wl_n);
    write_kernel<<<64, 256, 0, stream>>>(cw, blockoff, expbase, list);
    moe_gemm1<<<MAX_WL * 16, 256, 0, stream>>>(
        xb, w1b, b1, Hc, list, counts, expbase, wl, wl_n);
    moe_gemm2<<<MAX_WL * 4, 256, 0, stream>>>(
        Hc, w2b, b2, out, cw, list, counts, expbase, wl, wl_n);
  } else {
    short* Hb = (short*)(ws + 33816832);
    for (int e = 0; e < NEXP; ++e) {
      gemm_kernel<DIM, 0><<<dim3(HID / 128, N_TOK / 128), 256, 0, stream>>>(
          xb, w1b + (size_t)e * HID * DIM, b1 + (size_t)e * HID, Hb, nullptr, nullptr, e);
      if (e == 0)
        gemm_kernel<HID, 1><<<dim3(DIM / 128, N_TOK / 128), 256, 0, stream>>>(
            Hb, w2b + (size_t)e * DIM * HID, b2 + (size_t)e * DIM, nullptr, out, cw, e);
      else
        gemm_kernel<HID, 2><<<dim3(DIM / 128, N_TOK / 128), 256, 0, stream>>>(
            Hb, w2b + (size_t)e * DIM * HID, b2 + (size_t)e * DIM, nullptr, out, cw, e);
    }
  }
}

// Round 13
// 409.972 us; speedup vs baseline: 1.2715x; 1.2715x over previous
//
#include <hip/hip_runtime.h>
#include <hip/hip_bf16.h>
#include <cmath>
#include <cstdint>

#define N_TOK 16384
#define DIM   512
#define HID   2048
#define NEXP  4
#define MAX_WL 260   // sum_e ceil(cnt_e/128) <= 2*N_TOK/128 + NEXP

typedef __attribute__((ext_vector_type(8))) short bf16x8;
typedef __attribute__((ext_vector_type(4))) float f32x4;

__device__ __forceinline__ short f2bf(float f) {
  __hip_bfloat16 h = __float2bfloat16(f);
  return *reinterpret_cast<short*>(&h);
}

// gelu_gpt2(x) = 0.5x(1+tanh(c(x+0.044715x^3))) == x * sigmoid(2c(x+0.044715x^3))
__device__ __forceinline__ float gelu_f(float v) {
  float v2 = v * v;
  float u = v * (1.5957691216057308f + 0.07135481283254937f * v2);
  return v / (1.0f + __expf(-u));
}

__device__ __forceinline__ void load_lds16(const void* g, void* l) {
  __builtin_amdgcn_global_load_lds(
      (const __attribute__((address_space(1))) void*)g,
      (__attribute__((address_space(3))) void*)l, 16, 0, 0);
}

// swizzled LDS short-index for a (row, col16) fragment read.
#define LDSIDX(r, c16) (((r) * 64) + ((((c16) ^ ((r) & 7)) * 8)))

// ---------------- convert fp32 -> bf16 (vectorized x4) ----------------
__global__ void cvt_kernel(const float* __restrict__ src, short* __restrict__ dst, int n4) {
  int i = blockIdx.x * blockDim.x + threadIdx.x;
  int stride = gridDim.x * blockDim.x;
  for (; i < n4; i += stride) {
    float4 v = reinterpret_cast<const float4*>(src)[i];
    short4 o;
    o.x = f2bf(v.x); o.y = f2bf(v.y); o.z = f2bf(v.z); o.w = f2bf(v.w);
    reinterpret_cast<short4*>(dst)[i] = o;
  }
}

// ---------------- gate ----------------
__global__ __launch_bounds__(256) void gate_kernel(
    const float* __restrict__ x, const float* __restrict__ gw,
    float* __restrict__ cw, float* __restrict__ gate_sum,
    short* __restrict__ xb) {
  int t = threadIdx.x, wid = t >> 6, lane = t & 63;

  float4 g[NEXP][2];
#pragma unroll
  for (int e = 0; e < NEXP; ++e) {
    const float4* gp = reinterpret_cast<const float4*>(gw + e * DIM + lane * 8);
    g[e][0] = gp[0]; g[e][1] = gp[1];
  }

  float lsum = 0.0f;
  int n0 = blockIdx.x * 64 + wid * 16;
  for (int i = 0; i < 16; ++i) {
    int n = n0 + i;
    const float4* xr4 = reinterpret_cast<const float4*>(x + (size_t)n * DIM);
    float4 a = xr4[lane * 2];
    float4 b = xr4[lane * 2 + 1];

    short4 s0, s1;
    s0.x = f2bf(a.x); s0.y = f2bf(a.y); s0.z = f2bf(a.z); s0.w = f2bf(a.w);
    s1.x = f2bf(b.x); s1.y = f2bf(b.y); s1.z = f2bf(b.z); s1.w = f2bf(b.w);
    short4* xbp = reinterpret_cast<short4*>(xb + (size_t)n * DIM + lane * 8);
    xbp[0] = s0; xbp[1] = s1;

    float p[NEXP];
#pragma unroll
    for (int e = 0; e < NEXP; ++e) {
      p[e] = a.x * g[e][0].x + a.y * g[e][0].y + a.z * g[e][0].z + a.w * g[e][0].w
           + b.x * g[e][1].x + b.y * g[e][1].y + b.z * g[e][1].z + b.w * g[e][1].w;
    }
#pragma unroll
    for (int e = 0; e < NEXP; ++e)
#pragma unroll
      for (int off = 32; off; off >>= 1) p[e] += __shfl_xor(p[e], off);

    if (lane == 0) {
      lsum += p[0] + p[1] + p[2] + p[3];
      int i0 = 0;
#pragma unroll
      for (int e = 1; e < NEXP; ++e) if (p[e] > p[i0]) i0 = e;
      int i1 = -1;
#pragma unroll
      for (int e = 0; e < NEXP; ++e) {
        if (e == i0) continue;
        if (i1 < 0 || p[e] > p[i1]) i1 = e;
      }
      float eb = expf(p[i1] - p[i0]);
      float w0 = 1.0f / (1.0f + eb);
      float w1 = eb / (1.0f + eb);
      float row[NEXP] = {0.f, 0.f, 0.f, 0.f};
      row[i0] = w0; row[i1] = w1;
#pragma unroll
      for (int e = 0; e < NEXP; ++e) cw[n * NEXP + e] = row[e];
    }
  }
  __shared__ float bs[4];
  if (lane == 0) bs[wid] = lsum;
  __syncthreads();
  if (t == 0) atomicAdd(gate_sum, bs[0] + bs[1] + bs[2] + bs[3]);
}

__global__ void loss_kernel(const float* __restrict__ gate_sum, float* __restrict__ out_loss) {
  float m = gate_sum[0] / (float)(N_TOK * NEXP);
  out_loss[0] = m * logf(m + 0.1f);
}

// ---------------- compaction ----------------
__global__ __launch_bounds__(256) void count_kernel(const float* __restrict__ cw,
                                                    int* __restrict__ blockcnt) {
  __shared__ int c[4];
  int t = threadIdx.x;
  if (t < 4) c[t] = 0;
  __syncthreads();
  int n = blockIdx.x * 256 + t;
  float4 w = reinterpret_cast<const float4*>(cw)[n];
  unsigned long long m0 = __ballot(w.x != 0.f);
  unsigned long long m1 = __ballot(w.y != 0.f);
  unsigned long long m2 = __ballot(w.z != 0.f);
  unsigned long long m3 = __ballot(w.w != 0.f);
  if ((t & 63) == 0) {
    atomicAdd(&c[0], (int)__popcll(m0));
    atomicAdd(&c[1], (int)__popcll(m1));
    atomicAdd(&c[2], (int)__popcll(m2));
    atomicAdd(&c[3], (int)__popcll(m3));
  }
  __syncthreads();
  if (t < 4) blockcnt[blockIdx.x * 4 + t] = c[t];
}

// scan + build live-work-list of (expert, bm) row-tiles
__global__ void scan_kernel(const int* __restrict__ blockcnt, int* __restrict__ blockoff,
                            int* __restrict__ counts, int* __restrict__ expbase,
                            int* __restrict__ wl, int* __restrict__ wl_n) {
  int lane = threadIdx.x;  // 64
  int tot[NEXP];
#pragma unroll
  for (int e = 0; e < NEXP; ++e) {
    int v = blockcnt[lane * 4 + e];
    int inc = v;
#pragma unroll
    for (int off = 1; off < 64; off <<= 1) {
      int u = __shfl_up(inc, off);
      if (lane >= off) inc += u;
    }
    blockoff[lane * 4 + e] = inc - v;
    tot[e] = __shfl(inc, 63);
  }
  if (lane == 0) {
    int base = 0;
#pragma unroll
    for (int e = 0; e < NEXP; ++e) {
      counts[e] = tot[e];
      expbase[e] = base;
      base += tot[e];
    }
    int n = 0;
    for (int e = 0; e < NEXP; ++e) {
      int nb = (tot[e] + 127) >> 7;
      for (int b = 0; b < nb; ++b) wl[n++] = (e << 20) | b;
    }
    wl_n[0] = n;
  }
}

// stable index write + inverse map inv[n][k] = pos | (e<<20), k in ascending-e order
__global__ __launch_bounds__(256) void write_kernel(const float* __restrict__ cw,
                                                    const int* __restrict__ blockoff,
                                                    const int* __restrict__ expbase,
                                                    int* __restrict__ list,
                                                    int* __restrict__ inv) {
  int t = threadIdx.x, wave = t >> 6, lane = t & 63;
  int blk = blockIdx.x;
  int n = blk * 256 + t;
  float4 w4 = reinterpret_cast<const float4*>(cw)[n];
  float wf[4] = {w4.x, w4.y, w4.z, w4.w};
  __shared__ int wcnt[4][4];
  unsigned long long lt = (1ULL << lane) - 1ULL;
  int pfx[4]; bool sel[4];
#pragma unroll
  for (int e = 0; e < NEXP; ++e) {
    sel[e] = (wf[e] != 0.f);
    unsigned long long m = __ballot(sel[e]);
    pfx[e] = (int)__popcll(m & lt);
    if (lane == 0) wcnt[wave][e] = (int)__popcll(m);
  }
  __syncthreads();
  int kk = 0;
#pragma unroll
  for (int e = 0; e < NEXP; ++e) {
    if (sel[e]) {
      int woff = 0;
      for (int w2 = 0; w2 < wave; ++w2) woff += wcnt[w2][e];
      int pos = expbase[e] + blockoff[blk * 4 + e] + woff + pfx[e];
      list[pos] = n;
      inv[n * 2 + kk] = pos | (e << 20);
      ++kk;
    }
  }
}

// ---------------- routed GEMM1: worklist + XCD swizzle (round-10 structure) ----
__global__ __launch_bounds__(256) void moe_gemm1(
    const short* __restrict__ xb, const short* __restrict__ w1b,
    const float* __restrict__ b1, short* __restrict__ Hc,
    const int* __restrict__ list, const int* __restrict__ counts,
    const int* __restrict__ expbase, const int* __restrict__ wl,
    const int* __restrict__ wl_n) {
  int lg = ((blockIdx.x & 7) * (MAX_WL * 2)) + (blockIdx.x >> 3); // cpx = 4160/8 = 520
  int bn = lg & 15, widx = lg >> 4;
  if (widx >= wl_n[0]) return;
  int entry = wl[widx];
  int e = entry >> 20, bm = entry & 0xFFFFF;
  int cnt = counts[e];
  int base = expbase[e];
  int bm0 = bm * 128;
  int bn0 = bn * 128;
  const short* Bw = w1b + (size_t)e * HID * DIM;

  int t = threadIdx.x, lane = t & 63, wid = t >> 6;
  int srow = t >> 3;
  int scol = ((t & 7) ^ (srow & 7)) * 8;   // pre-swizzled global source column
  const short* Ag[4];
#pragma unroll
  for (int i = 0; i < 4; ++i) {
    int rc = bm0 + i * 32 + srow;
    int tok = list[base + ((rc < cnt) ? rc : 0)];
    Ag[i] = xb + (size_t)tok * DIM + scol;
  }
  const short* Bg = Bw + (size_t)(bn0 + srow) * DIM + scol;

  __shared__ __align__(16) short As[128 * 64];
  __shared__ __align__(16) short Bs[128 * 64];
  f32x4 acc[4][4] = {};
  int wr = (wid >> 1) * 64, wc = (wid & 1) * 64;

  for (int kt = 0; kt < DIM / 64; ++kt) {
    if (kt) __syncthreads();
    int k0 = kt * 64;
#pragma unroll
    for (int i = 0; i < 4; ++i) {
      load_lds16(Ag[i] + k0, As + i * 2048 + t * 8);
      load_lds16(Bg + (size_t)(i * 32) * DIM + k0, Bs + i * 2048 + t * 8);
    }
    __syncthreads();
#pragma unroll
    for (int ks = 0; ks < 2; ++ks) {
      bf16x8 af[4], bfr[4];
#pragma unroll
      for (int mi = 0; mi < 4; ++mi) {
        int r = wr + mi * 16 + (lane & 15);
        af[mi] = *(const bf16x8*)&As[LDSIDX(r, ks * 4 + (lane >> 4))];
      }
#pragma unroll
      for (int ni = 0; ni < 4; ++ni) {
        int r = wc + ni * 16 + (lane & 15);
        bfr[ni] = *(const bf16x8*)&Bs[LDSIDX(r, ks * 4 + (lane >> 4))];
      }
#pragma unroll
      for (int mi = 0; mi < 4; ++mi)
#pragma unroll
        for (int ni = 0; ni < 4; ++ni)
          acc[mi][ni] = __builtin_amdgcn_mfma_f32_16x16x32_bf16(af[mi], bfr[ni], acc[mi][ni], 0, 0, 0);
    }
  }

  int crow = (lane >> 4) * 4, ccol = lane & 15;
#pragma unroll
  for (int mi = 0; mi < 4; ++mi) {
#pragma unroll
    for (int ni = 0; ni < 4; ++ni) {
      int col = bn0 + wc + ni * 16 + ccol;
      float bv = b1[(size_t)e * HID + col];
#pragma unroll
      for (int j = 0; j < 4; ++j) {
        int rc = bm0 + wr + mi * 16 + crow + j;
        if (rc < cnt)
          Hc[(size_t)(base + rc) * HID + col] = f2bf(gelu_f(acc[mi][ni][j] + bv));
      }
    }
  }
}

// ---------------- routed GEMM2: round-10 structure; epilogue = compact store OR atomic ----
__global__ __launch_bounds__(256) void moe_gemm2(
    const short* __restrict__ Hc, const short* __restrict__ w2b,
    const float* __restrict__ b2, float* __restrict__ out,
    float* __restrict__ Oc, const float* __restrict__ cw,
    const int* __restrict__ list, const int* __restrict__ counts,
    const int* __restrict__ expbase, const int* __restrict__ wl,
    const int* __restrict__ wl_n, int use_compact) {
  int lg = ((blockIdx.x & 7) * (MAX_WL / 2)) + (blockIdx.x >> 3); // cpx = 1040/8 = 130
  int bn = lg & 3, widx = lg >> 2;
  if (widx >= wl_n[0]) return;
  int entry = wl[widx];
  int e = entry >> 20, bm = entry & 0xFFFFF;
  int cnt = counts[e];
  int base = expbase[e];
  int bm0 = bm * 128;
  int bn0 = bn * 128;
  const short* Bw = w2b + (size_t)e * DIM * HID;

  int t = threadIdx.x, lane = t & 63, wid = t >> 6;
  int srow = t >> 3;
  int scol = ((t & 7) ^ (srow & 7)) * 8;
  const short* Ag = Hc + (size_t)(base + bm0 + srow) * HID + scol;
  const short* Bg = Bw + (size_t)(bn0 + srow) * HID + scol;

  __shared__ __align__(16) short As[128 * 64];
  __shared__ __align__(16) short Bs[128 * 64];
  f32x4 acc[4][4] = {};
  int wr = (wid >> 1) * 64, wc = (wid & 1) * 64;

  for (int kt = 0; kt < HID / 64; ++kt) {
    if (kt) __syncthreads();
    int k0 = kt * 64;
#pragma unroll
    for (int i = 0; i < 4; ++i) {
      load_lds16(Ag + (size_t)(i * 32) * HID + k0, As + i * 2048 + t * 8);
      load_lds16(Bg + (size_t)(i * 32) * HID + k0, Bs + i * 2048 + t * 8);
    }
    __syncthreads();
#pragma unroll
    for (int ks = 0; ks < 2; ++ks) {
      bf16x8 af[4], bfr[4];
#pragma unroll
      for (int mi = 0; mi < 4; ++mi) {
        int r = wr + mi * 16 + (lane & 15);
        af[mi] = *(const bf16x8*)&As[LDSIDX(r, ks * 4 + (lane >> 4))];
      }
#pragma unroll
      for (int ni = 0; ni < 4; ++ni) {
        int r = wc + ni * 16 + (lane & 15);
        bfr[ni] = *(const bf16x8*)&Bs[LDSIDX(r, ks * 4 + (lane >> 4))];
      }
#pragma unroll
      for (int mi = 0; mi < 4; ++mi)
#pragma unroll
        for (int ni = 0; ni < 4; ++ni)
          acc[mi][ni] = __builtin_amdgcn_mfma_f32_16x16x32_bf16(af[mi], bfr[ni], acc[mi][ni], 0, 0, 0);
    }
  }

  int crow = (lane >> 4) * 4, ccol = lane & 15;
  if (use_compact) {
    // plain stores: Oc[base+rc][col] = acc + b2[e][col]; combine pass applies cw.
#pragma unroll
    for (int mi = 0; mi < 4; ++mi) {
#pragma unroll
      for (int ni = 0; ni < 4; ++ni) {
        int col = bn0 + wc + ni * 16 + ccol;
        float bv = b2[(size_t)e * DIM + col];
#pragma unroll
        for (int j = 0; j < 4; ++j) {
          int rc = bm0 + wr + mi * 16 + crow + j;
          if (rc < cnt)
            Oc[(size_t)(base + rc) * DIM + col] = acc[mi][ni][j] + bv;
        }
      }
    }
  } else {
#pragma unroll
    for (int mi = 0; mi < 4; ++mi) {
      int tokr[4]; float wgtr[4]; bool val[4];
#pragma unroll
      for (int j = 0; j < 4; ++j) {
        int rc = bm0 + wr + mi * 16 + crow + j;
        val[j] = (rc < cnt);
        int tok = list[base + (val[j] ? rc : 0)];
        tokr[j] = tok;
        wgtr[j] = cw[tok * NEXP + e];
      }
#pragma unroll
      for (int ni = 0; ni < 4; ++ni) {
        int col = bn0 + wc + ni * 16 + ccol;
        float bv = b2[(size_t)e * DIM + col];
#pragma unroll
        for (int j = 0; j < 4; ++j) {
          if (val[j])
            atomicAdd(&out[(size_t)tokr[j] * DIM + col], wgtr[j] * (acc[mi][ni][j] + bv));
        }
      }
    }
  }
}

// ---------------- combine: out[n] = w0*Oc[p0] + w1*Oc[p1] ----------------
__global__ __launch_bounds__(256) void combine_kernel(
    const float* __restrict__ Oc, const int* __restrict__ inv,
    const float* __restrict__ cw, float* __restrict__ out) {
  int i = blockIdx.x * 256 + threadIdx.x;     // float4 index, total N_TOK*DIM/4
  int n = i >> 7;                             // 128 float4 per token
  int c4 = i & 127;
  int v0 = inv[n * 2], v1 = inv[n * 2 + 1];
  int p0 = v0 & 0xFFFFF, e0 = v0 >> 20;
  int p1 = v1 & 0xFFFFF, e1 = v1 >> 20;
  float w0 = cw[n * NEXP + e0];
  float w1 = cw[n * NEXP + e1];
  const float4* O4 = reinterpret_cast<const float4*>(Oc);
  float4 a = O4[(size_t)p0 * 128 + c4];
  float4 b = O4[(size_t)p1 * 128 + c4];
  float4 o;
  o.x = w0 * a.x + w1 * b.x;
  o.y = w0 * a.y + w1 * b.y;
  o.z = w0 * a.z + w1 * b.z;
  o.w = w0 * a.w + w1 * b.w;
  reinterpret_cast<float4*>(out)[i] = o;
}

// ---------------- dense fallback GEMM ----------------
template <int KDIM, int EPI>
__global__ __launch_bounds__(256) void gemm_kernel(
    const short* __restrict__ A, const short* __restrict__ B,
    const float* __restrict__ bias,
    short* __restrict__ Hout, float* __restrict__ out,
    const float* __restrict__ cw, int expert) {
  constexpr int BK = 64;
  __shared__ __align__(16) short As[128 * BK];
  __shared__ __align__(16) short Bs[128 * BK];
  int t = threadIdx.x;
  int lane = t & 63, wid = t >> 6;
  int bn0 = blockIdx.x * 128;
  int bm0 = blockIdx.y * 128;
  int wr = (wid >> 1) * 64;
  int wc = (wid & 1) * 64;
  f32x4 acc[4][4] = {};
  int srow = t >> 3;
  int scol = (t & 7) * 8;
  const short* Ag = A + (size_t)(bm0 + srow) * KDIM + scol;
  const short* Bg = B + (size_t)(bn0 + srow) * KDIM + scol;
  for (int kt = 0; kt < KDIM / BK; ++kt) {
    if (kt) __syncthreads();
    int k0 = kt * BK;
#pragma unroll
    for (int i = 0; i < 4; ++i) {
      load_lds16(Ag + (size_t)(i * 32) * KDIM + k0, As + i * 2048 + t * 8);
      load_lds16(Bg + (size_t)(i * 32) * KDIM + k0, Bs + i * 2048 + t * 8);
    }
    __syncthreads();
#pragma unroll
    for (int ks = 0; ks < 2; ++ks) {
      int koff = ks * 32 + ((lane >> 4) << 3);
      bf16x8 af[4], bfr[4];
#pragma unroll
      for (int mi = 0; mi < 4; ++mi)
        af[mi] = *(const bf16x8*)&As[(wr + mi * 16 + (lane & 15)) * BK + koff];
#pragma unroll
      for (int ni = 0; ni < 4; ++ni)
        bfr[ni] = *(const bf16x8*)&Bs[(wc + ni * 16 + (lane & 15)) * BK + koff];
#pragma unroll
      for (int mi = 0; mi < 4; ++mi)
#pragma unroll
        for (int ni = 0; ni < 4; ++ni)
          acc[mi][ni] = __builtin_amdgcn_mfma_f32_16x16x32_bf16(af[mi], bfr[ni], acc[mi][ni], 0, 0, 0);
    }
  }
  int crow = (lane >> 4) * 4;
  int ccol = lane & 15;
#pragma unroll
  for (int mi = 0; mi < 4; ++mi) {
#pragma unroll
    for (int ni = 0; ni < 4; ++ni) {
      int col = bn0 + wc + ni * 16 + ccol;
      float bv = bias[col];
#pragma unroll
      for (int j = 0; j < 4; ++j) {
        int row = bm0 + wr + mi * 16 + crow + j;
        float v = acc[mi][ni][j] + bv;
        if constexpr (EPI == 0) {
          Hout[(size_t)row * HID + col] = f2bf(gelu_f(v));
        } else {
          float w = cw[row * NEXP + expert];
          float r = w * v;
          if constexpr (EPI == 1) out[(size_t)row * DIM + col] = r;
          else                    out[(size_t)row * DIM + col] += r;
        }
      }
    }
  }
}

extern "C" void kernel_launch(void* const* d_in, const int* in_sizes, int n_in,
                              void* d_out, int out_size, void* d_ws, size_t ws_size,
                              hipStream_t stream) {
  const float* x  = (const float*)d_in[0];
  const float* gw = (const float*)d_in[1];
  const float* w1 = (const float*)d_in[2];
  const float* b1 = (const float*)d_in[3];
  const float* w2 = (const float*)d_in[4];
  const float* b2 = (const float*)d_in[5];
  float* out = (float*)d_out;

  char* ws = (char*)d_ws;
  float* cw       = (float*)(ws + 0);            // 262144 B
  float* gate_sum = (float*)(ws + 262144);       // pad to 262400
  int*   blockcnt = (int*)(ws + 262400);         // 1024 B
  int*   blockoff = (int*)(ws + 263424);         // 1024 B
  int*   counts   = (int*)(ws + 264448);         // 64 B
  int*   expbase  = (int*)(ws + 264512);         // 64 B
  int*   wl_n     = (int*)(ws + 264576);         // 64 B
  int*   wl       = (int*)(ws + 264640);         // 1536 B -> 266176
  int*   list     = (int*)(ws + 266176);         // 131072 B -> 397248
  int*   inv      = (int*)(ws + 397248);         // 131072 B -> 528320
  short* xb       = (short*)(ws + 528320);       // 16 MB -> 17305536
  short* w1b      = (short*)(ws + 17305536);     // 8 MB  -> 25694144
  short* w2b      = (short*)(ws + 25694144);     // 8 MB  -> 34082752
  short* Hc       = (short*)(ws + 34082752);     // (32768+128)*2048*2 -> 168824768
  float* Oc       = (float*)(ws + 168824768);    // (32768+128)*512*4  -> 236195776
  const size_t ROUTED_NEED  = 168824768ull;
  const size_t COMPACT_NEED = 236195776ull;
  int use_compact = (ws_size >= COMPACT_NEED) ? 1 : 0;

  hipMemsetAsync(gate_sum, 0, sizeof(float), stream);
  cvt_kernel<<<1024, 256, 0, stream>>>(w1, w1b, NEXP * HID * DIM / 4);
  cvt_kernel<<<1024, 256, 0, stream>>>(w2, w2b, NEXP * DIM * HID / 4);
  gate_kernel<<<N_TOK / 64, 256, 0, stream>>>(x, gw, cw, gate_sum, xb);
  loss_kernel<<<1, 1, 0, stream>>>(gate_sum, out + (size_t)N_TOK * DIM);

  if (ws_size >= ROUTED_NEED) {
    if (!use_compact)
      hipMemsetAsync(out, 0, (size_t)N_TOK * DIM * sizeof(float), stream);
    count_kernel<<<64, 256, 0, stream>>>(cw, blockcnt);
    scan_kernel<<<1, 64, 0, stream>>>(blockcnt, blockoff, counts, expbase, wl, wl_n);
    write_kernel<<<64, 256, 0, stream>>>(cw, blockoff, expbase, list, inv);
    moe_gemm1<<<MAX_WL * 16, 256, 0, stream>>>(
        xb, w1b, b1, Hc, list, counts, expbase, wl, wl_n);
    moe_gemm2<<<MAX_WL * 4, 256, 0, stream>>>(
        Hc, w2b, b2, out, Oc, cw, list, counts, expbase, wl, wl_n, use_compact);
    if (use_compact)
      combine_kernel<<<N_TOK * DIM / 4 / 256, 256, 0, stream>>>(Oc, inv, cw, out);
  } else {
    short* Hb = (short*)(ws + 33816832);
    for (int e = 0; e < NEXP; ++e) {
      gemm_kernel<DIM, 0><<<dim3(HID / 128, N_TOK / 128), 256, 0, stream>>>(
          xb, w1b + (size_t)e * HID * DIM, b1 + (size_t)e * HID, Hb, nullptr, nullptr, e);
      if (e == 0)
        gemm_kernel<HID, 1><<<dim3(DIM / 128, N_TOK / 128), 256, 0, stream>>>(
            Hb, w2b + (size_t)e * DIM * HID, b2 + (size_t)e * DIM, nullptr, out, cw, e);
      else
        gemm_kernel<HID, 2><<<dim3(DIM / 128, N_TOK / 128), 256, 0, stream>>>(
            Hb, w2b + (size_t)e * DIM * HID, b2 + (size_t)e * DIM, nullptr, out, cw, e);
    }
  }
}

// Round 14
// 399.372 us; speedup vs baseline: 1.3052x; 1.0265x over previous
//
#include <hip/hip_runtime.h>
#include <hip/hip_bf16.h>
#include <cmath>
#include <cstdint>

#define N_TOK 16384
#define DIM   512
#define HID   2048
#define NEXP  4
#define MAX_WL 260   // sum_e ceil(cnt_e/128) <= 2*N_TOK/128 + NEXP

typedef __attribute__((ext_vector_type(8))) short bf16x8;
typedef __attribute__((ext_vector_type(4))) float f32x4;

__device__ __forceinline__ short f2bf(float f) {
  __hip_bfloat16 h = __float2bfloat16(f);
  return *reinterpret_cast<short*>(&h);
}

// gelu_gpt2(x) = 0.5x(1+tanh(c(x+0.044715x^3))) == x * sigmoid(2c(x+0.044715x^3))
__device__ __forceinline__ float gelu_f(float v) {
  float v2 = v * v;
  float u = v * (1.5957691216057308f + 0.07135481283254937f * v2);
  return v / (1.0f + __expf(-u));
}

__device__ __forceinline__ void load_lds16(const void* g, void* l) {
  __builtin_amdgcn_global_load_lds(
      (const __attribute__((address_space(1))) void*)g,
      (__attribute__((address_space(3))) void*)l, 16, 0, 0);
}

// swizzled LDS short-index for a (row, col16) fragment read.
#define LDSIDX(r, c16) (((r) * 64) + ((((c16) ^ ((r) & 7)) * 8)))

// ---------------- convert fp32 -> bf16 (vectorized x4) ----------------
__global__ void cvt_kernel(const float* __restrict__ src, short* __restrict__ dst, int n4) {
  int i = blockIdx.x * blockDim.x + threadIdx.x;
  int stride = gridDim.x * blockDim.x;
  for (; i < n4; i += stride) {
    float4 v = reinterpret_cast<const float4*>(src)[i];
    short4 o;
    o.x = f2bf(v.x); o.y = f2bf(v.y); o.z = f2bf(v.z); o.w = f2bf(v.w);
    reinterpret_cast<short4*>(dst)[i] = o;
  }
}

// ---------------- gate: 1 token per wave, 4096 blocks, no atomics ----------------
__global__ __launch_bounds__(256) void gate_kernel(
    const float* __restrict__ x, const float* __restrict__ gw,
    float* __restrict__ cw, float* __restrict__ gsum_part,
    short* __restrict__ xb) {
  int t = threadIdx.x, wid = t >> 6, lane = t & 63;

  float4 g[NEXP][2];
#pragma unroll
  for (int e = 0; e < NEXP; ++e) {
    const float4* gp = reinterpret_cast<const float4*>(gw + e * DIM + lane * 8);
    g[e][0] = gp[0]; g[e][1] = gp[1];
  }

  int n = blockIdx.x * 4 + wid;
  const float4* xr4 = reinterpret_cast<const float4*>(x + (size_t)n * DIM);
  float4 a = xr4[lane * 2];
  float4 b = xr4[lane * 2 + 1];

  // fused x -> bf16
  short4 s0, s1;
  s0.x = f2bf(a.x); s0.y = f2bf(a.y); s0.z = f2bf(a.z); s0.w = f2bf(a.w);
  s1.x = f2bf(b.x); s1.y = f2bf(b.y); s1.z = f2bf(b.z); s1.w = f2bf(b.w);
  short4* xbp = reinterpret_cast<short4*>(xb + (size_t)n * DIM + lane * 8);
  xbp[0] = s0; xbp[1] = s1;

  float p[NEXP];
#pragma unroll
  for (int e = 0; e < NEXP; ++e) {
    p[e] = a.x * g[e][0].x + a.y * g[e][0].y + a.z * g[e][0].z + a.w * g[e][0].w
         + b.x * g[e][1].x + b.y * g[e][1].y + b.z * g[e][1].z + b.w * g[e][1].w;
  }
#pragma unroll
  for (int e = 0; e < NEXP; ++e)
#pragma unroll
    for (int off = 32; off; off >>= 1) p[e] += __shfl_xor(p[e], off);

  __shared__ float bs[4];
  if (lane == 0) {
    bs[wid] = p[0] + p[1] + p[2] + p[3];
    int i0 = 0;
#pragma unroll
    for (int e = 1; e < NEXP; ++e) if (p[e] > p[i0]) i0 = e;
    int i1 = -1;
#pragma unroll
    for (int e = 0; e < NEXP; ++e) {
      if (e == i0) continue;
      if (i1 < 0 || p[e] > p[i1]) i1 = e;
    }
    float eb = expf(p[i1] - p[i0]);
    float w0 = 1.0f / (1.0f + eb);
    float w1 = eb / (1.0f + eb);
    float row[NEXP] = {0.f, 0.f, 0.f, 0.f};
    row[i0] = w0; row[i1] = w1;
#pragma unroll
    for (int e = 0; e < NEXP; ++e) cw[n * NEXP + e] = row[e];
  }
  __syncthreads();
  if (t == 0) gsum_part[blockIdx.x] = bs[0] + bs[1] + bs[2] + bs[3];
}

// reduce 4096 partials -> loss
__global__ __launch_bounds__(256) void loss_kernel(const float* __restrict__ gsum_part,
                                                   float* __restrict__ out_loss) {
  __shared__ float sh[4];
  int t = threadIdx.x;
  float s = 0.f;
  for (int i = t; i < 4096; i += 256) s += gsum_part[i];
#pragma unroll
  for (int off = 32; off; off >>= 1) s += __shfl_xor(s, off);
  if ((t & 63) == 0) sh[t >> 6] = s;
  __syncthreads();
  if (t == 0) {
    float m = (sh[0] + sh[1] + sh[2] + sh[3]) / (float)(N_TOK * NEXP);
    out_loss[0] = m * logf(m + 0.1f);
  }
}

// ---------------- compaction ----------------
__global__ __launch_bounds__(256) void count_kernel(const float* __restrict__ cw,
                                                    int* __restrict__ blockcnt) {
  __shared__ int c[4];
  int t = threadIdx.x;
  if (t < 4) c[t] = 0;
  __syncthreads();
  int n = blockIdx.x * 256 + t;
  float4 w = reinterpret_cast<const float4*>(cw)[n];
  unsigned long long m0 = __ballot(w.x != 0.f);
  unsigned long long m1 = __ballot(w.y != 0.f);
  unsigned long long m2 = __ballot(w.z != 0.f);
  unsigned long long m3 = __ballot(w.w != 0.f);
  if ((t & 63) == 0) {
    atomicAdd(&c[0], (int)__popcll(m0));
    atomicAdd(&c[1], (int)__popcll(m1));
    atomicAdd(&c[2], (int)__popcll(m2));
    atomicAdd(&c[3], (int)__popcll(m3));
  }
  __syncthreads();
  if (t < 4) blockcnt[blockIdx.x * 4 + t] = c[t];
}

// scan + build live-work-list of (expert, bm) row-tiles
__global__ void scan_kernel(const int* __restrict__ blockcnt, int* __restrict__ blockoff,
                            int* __restrict__ counts, int* __restrict__ expbase,
                            int* __restrict__ wl, int* __restrict__ wl_n) {
  int lane = threadIdx.x;  // 64
  int tot[NEXP];
#pragma unroll
  for (int e = 0; e < NEXP; ++e) {
    int v = blockcnt[lane * 4 + e];
    int inc = v;
#pragma unroll
    for (int off = 1; off < 64; off <<= 1) {
      int u = __shfl_up(inc, off);
      if (lane >= off) inc += u;
    }
    blockoff[lane * 4 + e] = inc - v;
    tot[e] = __shfl(inc, 63);
  }
  if (lane == 0) {
    int base = 0;
#pragma unroll
    for (int e = 0; e < NEXP; ++e) {
      counts[e] = tot[e];
      expbase[e] = base;
      base += tot[e];
    }
    int n = 0;
    for (int e = 0; e < NEXP; ++e) {
      int nb = (tot[e] + 127) >> 7;
      for (int b = 0; b < nb; ++b) wl[n++] = (e << 20) | b;
    }
    wl_n[0] = n;
  }
}

// stable index write + inverse map inv[n][k] = pos | (e<<20), k in ascending-e order
__global__ __launch_bounds__(256) void write_kernel(const float* __restrict__ cw,
                                                    const int* __restrict__ blockoff,
                                                    const int* __restrict__ expbase,
                                                    int* __restrict__ list,
                                                    int* __restrict__ inv) {
  int t = threadIdx.x, wave = t >> 6, lane = t & 63;
  int blk = blockIdx.x;
  int n = blk * 256 + t;
  float4 w4 = reinterpret_cast<const float4*>(cw)[n];
  float wf[4] = {w4.x, w4.y, w4.z, w4.w};
  __shared__ int wcnt[4][4];
  unsigned long long lt = (1ULL << lane) - 1ULL;
  int pfx[4]; bool sel[4];
#pragma unroll
  for (int e = 0; e < NEXP; ++e) {
    sel[e] = (wf[e] != 0.f);
    unsigned long long m = __ballot(sel[e]);
    pfx[e] = (int)__popcll(m & lt);
    if (lane == 0) wcnt[wave][e] = (int)__popcll(m);
  }
  __syncthreads();
  int kk = 0;
#pragma unroll
  for (int e = 0; e < NEXP; ++e) {
    if (sel[e]) {
      int woff = 0;
      for (int w2 = 0; w2 < wave; ++w2) woff += wcnt[w2][e];
      int pos = expbase[e] + blockoff[blk * 4 + e] + woff + pfx[e];
      list[pos] = n;
      inv[n * 2 + kk] = pos | (e << 20);
      ++kk;
    }
  }
}

// ---------------- routed GEMM1: worklist + XCD swizzle (round-10 structure) ----
__global__ __launch_bounds__(256) void moe_gemm1(
    const short* __restrict__ xb, const short* __restrict__ w1b,
    const float* __restrict__ b1, short* __restrict__ Hc,
    const int* __restrict__ list, const int* __restrict__ counts,
    const int* __restrict__ expbase, const int* __restrict__ wl,
    const int* __restrict__ wl_n) {
  int lg = ((blockIdx.x & 7) * (MAX_WL * 2)) + (blockIdx.x >> 3); // cpx = 4160/8 = 520
  int bn = lg & 15, widx = lg >> 4;
  if (widx >= wl_n[0]) return;
  int entry = wl[widx];
  int e = entry >> 20, bm = entry & 0xFFFFF;
  int cnt = counts[e];
  int base = expbase[e];
  int bm0 = bm * 128;
  int bn0 = bn * 128;
  const short* Bw = w1b + (size_t)e * HID * DIM;

  int t = threadIdx.x, lane = t & 63, wid = t >> 6;
  int srow = t >> 3;
  int scol = ((t & 7) ^ (srow & 7)) * 8;   // pre-swizzled global source column
  const short* Ag[4];
#pragma unroll
  for (int i = 0; i < 4; ++i) {
    int rc = bm0 + i * 32 + srow;
    int tok = list[base + ((rc < cnt) ? rc : 0)];
    Ag[i] = xb + (size_t)tok * DIM + scol;
  }
  const short* Bg = Bw + (size_t)(bn0 + srow) * DIM + scol;

  __shared__ __align__(16) short As[128 * 64];
  __shared__ __align__(16) short Bs[128 * 64];
  f32x4 acc[4][4] = {};
  int wr = (wid >> 1) * 64, wc = (wid & 1) * 64;

  for (int kt = 0; kt < DIM / 64; ++kt) {
    if (kt) __syncthreads();
    int k0 = kt * 64;
#pragma unroll
    for (int i = 0; i < 4; ++i) {
      load_lds16(Ag[i] + k0, As + i * 2048 + t * 8);
      load_lds16(Bg + (size_t)(i * 32) * DIM + k0, Bs + i * 2048 + t * 8);
    }
    __syncthreads();
#pragma unroll
    for (int ks = 0; ks < 2; ++ks) {
      bf16x8 af[4], bfr[4];
#pragma unroll
      for (int mi = 0; mi < 4; ++mi) {
        int r = wr + mi * 16 + (lane & 15);
        af[mi] = *(const bf16x8*)&As[LDSIDX(r, ks * 4 + (lane >> 4))];
      }
#pragma unroll
      for (int ni = 0; ni < 4; ++ni) {
        int r = wc + ni * 16 + (lane & 15);
        bfr[ni] = *(const bf16x8*)&Bs[LDSIDX(r, ks * 4 + (lane >> 4))];
      }
#pragma unroll
      for (int mi = 0; mi < 4; ++mi)
#pragma unroll
        for (int ni = 0; ni < 4; ++ni)
          acc[mi][ni] = __builtin_amdgcn_mfma_f32_16x16x32_bf16(af[mi], bfr[ni], acc[mi][ni], 0, 0, 0);
    }
  }

  int crow = (lane >> 4) * 4, ccol = lane & 15;
#pragma unroll
  for (int mi = 0; mi < 4; ++mi) {
#pragma unroll
    for (int ni = 0; ni < 4; ++ni) {
      int col = bn0 + wc + ni * 16 + ccol;
      float bv = b1[(size_t)e * HID + col];
#pragma unroll
      for (int j = 0; j < 4; ++j) {
        int rc = bm0 + wr + mi * 16 + crow + j;
        if (rc < cnt)
          Hc[(size_t)(base + rc) * HID + col] = f2bf(gelu_f(acc[mi][ni][j] + bv));
      }
    }
  }
}

// ---------------- routed GEMM2: round-10 structure; epilogue = compact store OR atomic ----
__global__ __launch_bounds__(256) void moe_gemm2(
    const short* __restrict__ Hc, const short* __restrict__ w2b,
    const float* __restrict__ b2, float* __restrict__ out,
    float* __restrict__ Oc, const float* __restrict__ cw,
    const int* __restrict__ list, const int* __restrict__ counts,
    const int* __restrict__ expbase, const int* __restrict__ wl,
    const int* __restrict__ wl_n, int use_compact) {
  int lg = ((blockIdx.x & 7) * (MAX_WL / 2)) + (blockIdx.x >> 3); // cpx = 1040/8 = 130
  int bn = lg & 3, widx = lg >> 2;
  if (widx >= wl_n[0]) return;
  int entry = wl[widx];
  int e = entry >> 20, bm = entry & 0xFFFFF;
  int cnt = counts[e];
  int base = expbase[e];
  int bm0 = bm * 128;
  int bn0 = bn * 128;
  const short* Bw = w2b + (size_t)e * DIM * HID;

  int t = threadIdx.x, lane = t & 63, wid = t >> 6;
  int srow = t >> 3;
  int scol = ((t & 7) ^ (srow & 7)) * 8;
  const short* Ag = Hc + (size_t)(base + bm0 + srow) * HID + scol;
  const short* Bg = Bw + (size_t)(bn0 + srow) * HID + scol;

  __shared__ __align__(16) short As[128 * 64];
  __shared__ __align__(16) short Bs[128 * 64];
  f32x4 acc[4][4] = {};
  int wr = (wid >> 1) * 64, wc = (wid & 1) * 64;

  for (int kt = 0; kt < HID / 64; ++kt) {
    if (kt) __syncthreads();
    int k0 = kt * 64;
#pragma unroll
    for (int i = 0; i < 4; ++i) {
      load_lds16(Ag + (size_t)(i * 32) * HID + k0, As + i * 2048 + t * 8);
      load_lds16(Bg + (size_t)(i * 32) * HID + k0, Bs + i * 2048 + t * 8);
    }
    __syncthreads();
#pragma unroll
    for (int ks = 0; ks < 2; ++ks) {
      bf16x8 af[4], bfr[4];
#pragma unroll
      for (int mi = 0; mi < 4; ++mi) {
        int r = wr + mi * 16 + (lane & 15);
        af[mi] = *(const bf16x8*)&As[LDSIDX(r, ks * 4 + (lane >> 4))];
      }
#pragma unroll
      for (int ni = 0; ni < 4; ++ni) {
        int r = wc + ni * 16 + (lane & 15);
        bfr[ni] = *(const bf16x8*)&Bs[LDSIDX(r, ks * 4 + (lane >> 4))];
      }
#pragma unroll
      for (int mi = 0; mi < 4; ++mi)
#pragma unroll
        for (int ni = 0; ni < 4; ++ni)
          acc[mi][ni] = __builtin_amdgcn_mfma_f32_16x16x32_bf16(af[mi], bfr[ni], acc[mi][ni], 0, 0, 0);
    }
  }

  int crow = (lane >> 4) * 4, ccol = lane & 15;
  if (use_compact) {
    // plain stores: Oc[base+rc][col] = acc + b2[e][col]; combine pass applies cw.
#pragma unroll
    for (int mi = 0; mi < 4; ++mi) {
#pragma unroll
      for (int ni = 0; ni < 4; ++ni) {
        int col = bn0 + wc + ni * 16 + ccol;
        float bv = b2[(size_t)e * DIM + col];
#pragma unroll
        for (int j = 0; j < 4; ++j) {
          int rc = bm0 + wr + mi * 16 + crow + j;
          if (rc < cnt)
            Oc[(size_t)(base + rc) * DIM + col] = acc[mi][ni][j] + bv;
        }
      }
    }
  } else {
#pragma unroll
    for (int mi = 0; mi < 4; ++mi) {
      int tokr[4]; float wgtr[4]; bool val[4];
#pragma unroll
      for (int j = 0; j < 4; ++j) {
        int rc = bm0 + wr + mi * 16 + crow + j;
        val[j] = (rc < cnt);
        int tok = list[base + (val[j] ? rc : 0)];
        tokr[j] = tok;
        wgtr[j] = cw[tok * NEXP + e];
      }
#pragma unroll
      for (int ni = 0; ni < 4; ++ni) {
        int col = bn0 + wc + ni * 16 + ccol;
        float bv = b2[(size_t)e * DIM + col];
#pragma unroll
        for (int j = 0; j < 4; ++j) {
          if (val[j])
            atomicAdd(&out[(size_t)tokr[j] * DIM + col], wgtr[j] * (acc[mi][ni][j] + bv));
        }
      }
    }
  }
}

// ---------------- combine: out[n] = w0*Oc[p0] + w1*Oc[p1] ----------------
__global__ __launch_bounds__(256) void combine_kernel(
    const float* __restrict__ Oc, const int* __restrict__ inv,
    const float* __restrict__ cw, float* __restrict__ out) {
  int i = blockIdx.x * 256 + threadIdx.x;     // float4 index, total N_TOK*DIM/4
  int n = i >> 7;                             // 128 float4 per token
  int c4 = i & 127;
  int v0 = inv[n * 2], v1 = inv[n * 2 + 1];
  int p0 = v0 & 0xFFFFF, e0 = v0 >> 20;
  int p1 = v1 & 0xFFFFF, e1 = v1 >> 20;
  float w0 = cw[n * NEXP + e0];
  float w1 = cw[n * NEXP + e1];
  const float4* O4 = reinterpret_cast<const float4*>(Oc);
  float4 a = O4[(size_t)p0 * 128 + c4];
  float4 b = O4[(size_t)p1 * 128 + c4];
  float4 o;
  o.x = w0 * a.x + w1 * b.x;
  o.y = w0 * a.y + w1 * b.y;
  o.z = w0 * a.z + w1 * b.z;
  o.w = w0 * a.w + w1 * b.w;
  reinterpret_cast<float4*>(out)[i] = o;
}

// ---------------- dense fallback GEMM ----------------
template <int KDIM, int EPI>
__global__ __launch_bounds__(256) void gemm_kernel(
    const short* __restrict__ A, const short* __restrict__ B,
    const float* __restrict__ bias,
    short* __restrict__ Hout, float* __restrict__ out,
    const float* __restrict__ cw, int expert) {
  constexpr int BK = 64;
  __shared__ __align__(16) short As[128 * BK];
  __shared__ __align__(16) short Bs[128 * BK];
  int t = threadIdx.x;
  int lane = t & 63, wid = t >> 6;
  int bn0 = blockIdx.x * 128;
  int bm0 = blockIdx.y * 128;
  int wr = (wid >> 1) * 64;
  int wc = (wid & 1) * 64;
  f32x4 acc[4][4] = {};
  int srow = t >> 3;
  int scol = (t & 7) * 8;
  const short* Ag = A + (size_t)(bm0 + srow) * KDIM + scol;
  const short* Bg = B + (size_t)(bn0 + srow) * KDIM + scol;
  for (int kt = 0; kt < KDIM / BK; ++kt) {
    if (kt) __syncthreads();
    int k0 = kt * BK;
#pragma unroll
    for (int i = 0; i < 4; ++i) {
      load_lds16(Ag + (size_t)(i * 32) * KDIM + k0, As + i * 2048 + t * 8);
      load_lds16(Bg + (size_t)(i * 32) * KDIM + k0, Bs + i * 2048 + t * 8);
    }
    __syncthreads();
#pragma unroll
    for (int ks = 0; ks < 2; ++ks) {
      int koff = ks * 32 + ((lane >> 4) << 3);
      bf16x8 af[4], bfr[4];
#pragma unroll
      for (int mi = 0; mi < 4; ++mi)
        af[mi] = *(const bf16x8*)&As[(wr + mi * 16 + (lane & 15)) * BK + koff];
#pragma unroll
      for (int ni = 0; ni < 4; ++ni)
        bfr[ni] = *(const bf16x8*)&Bs[(wc + ni * 16 + (lane & 15)) * BK + koff];
#pragma unroll
      for (int mi = 0; mi < 4; ++mi)
#pragma unroll
        for (int ni = 0; ni < 4; ++ni)
          acc[mi][ni] = __builtin_amdgcn_mfma_f32_16x16x32_bf16(af[mi], bfr[ni], acc[mi][ni], 0, 0, 0);
    }
  }
  int crow = (lane >> 4) * 4;
  int ccol = lane & 15;
#pragma unroll
  for (int mi = 0; mi < 4; ++mi) {
#pragma unroll
    for (int ni = 0; ni < 4; ++ni) {
      int col = bn0 + wc + ni * 16 + ccol;
      float bv = bias[col];
#pragma unroll
      for (int j = 0; j < 4; ++j) {
        int row = bm0 + wr + mi * 16 + crow + j;
        float v = acc[mi][ni][j] + bv;
        if constexpr (EPI == 0) {
          Hout[(size_t)row * HID + col] = f2bf(gelu_f(v));
        } else {
          float w = cw[row * NEXP + expert];
          float r = w * v;
          if constexpr (EPI == 1) out[(size_t)row * DIM + col] = r;
          else                    out[(size_t)row * DIM + col] += r;
        }
      }
    }
  }
}

extern "C" void kernel_launch(void* const* d_in, const int* in_sizes, int n_in,
                              void* d_out, int out_size, void* d_ws, size_t ws_size,
                              hipStream_t stream) {
  const float* x  = (const float*)d_in[0];
  const float* gw = (const float*)d_in[1];
  const float* w1 = (const float*)d_in[2];
  const float* b1 = (const float*)d_in[3];
  const float* w2 = (const float*)d_in[4];
  const float* b2 = (const float*)d_in[5];
  float* out = (float*)d_out;

  char* ws = (char*)d_ws;
  float* cw        = (float*)(ws + 0);            // 262144 B
  int*   blockcnt  = (int*)(ws + 262400);         // 1024 B
  int*   blockoff  = (int*)(ws + 263424);         // 1024 B
  int*   counts    = (int*)(ws + 264448);         // 64 B
  int*   expbase   = (int*)(ws + 264512);         // 64 B
  int*   wl_n      = (int*)(ws + 264576);         // 64 B
  int*   wl        = (int*)(ws + 264640);         // 1536 B -> 266176
  float* gsum_part = (float*)(ws + 266176);       // 16384 B -> 282560
  int*   list      = (int*)(ws + 282560);         // 131072 B -> 413632
  int*   inv       = (int*)(ws + 413632);         // 131072 B -> 544704
  short* xb        = (short*)(ws + 544704);       // 16 MB -> 17321920
  short* w1b       = (short*)(ws + 17321920);     // 8 MB  -> 25710528
  short* w2b       = (short*)(ws + 25710528);     // 8 MB  -> 34099136
  short* Hc        = (short*)(ws + 34099136);     // (32768+128)*2048*2 -> 168841152
  float* Oc        = (float*)(ws + 168841152);    // (32768+128)*512*4  -> 236212160
  const size_t ROUTED_NEED  = 168841152ull;
  const size_t COMPACT_NEED = 236212160ull;
  int use_compact = (ws_size >= COMPACT_NEED) ? 1 : 0;

  cvt_kernel<<<1024, 256, 0, stream>>>(w1, w1b, NEXP * HID * DIM / 4);
  cvt_kernel<<<1024, 256, 0, stream>>>(w2, w2b, NEXP * DIM * HID / 4);
  gate_kernel<<<N_TOK / 4, 256, 0, stream>>>(x, gw, cw, gsum_part, xb);
  loss_kernel<<<1, 256, 0, stream>>>(gsum_part, out + (size_t)N_TOK * DIM);

  if (ws_size >= ROUTED_NEED) {
    if (!use_compact)
      hipMemsetAsync(out, 0, (size_t)N_TOK * DIM * sizeof(float), stream);
    count_kernel<<<64, 256, 0, stream>>>(cw, blockcnt);
    scan_kernel<<<1, 64, 0, stream>>>(blockcnt, blockoff, counts, expbase, wl, wl_n);
    write_kernel<<<64, 256, 0, stream>>>(cw, blockoff, expbase, list, inv);
    moe_gemm1<<<MAX_WL * 16, 256, 0, stream>>>(
        xb, w1b, b1, Hc, list, counts, expbase, wl, wl_n);
    moe_gemm2<<<MAX_WL * 4, 256, 0, stream>>>(
        Hc, w2b, b2, out, Oc, cw, list, counts, expbase, wl, wl_n, use_compact);
    if (use_compact)
      combine_kernel<<<N_TOK * DIM / 4 / 256, 256, 0, stream>>>(Oc, inv, cw, out);
  } else {
    short* Hb = (short*)(ws + 34099136);
    for (int e = 0; e < NEXP; ++e) {
      gemm_kernel<DIM, 0><<<dim3(HID / 128, N_TOK / 128), 256, 0, stream>>>(
          xb, w1b + (size_t)e * HID * DIM, b1 + (size_t)e * HID, Hb, nullptr, nullptr, e);
      if (e == 0)
        gemm_kernel<HID, 1><<<dim3(DIM / 128, N_TOK / 128), 256, 0, stream>>>(
            Hb, w2b + (size_t)e * DIM * HID, b2 + (size_t)e * DIM, nullptr, out, cw, e);
      else
        gemm_kernel<HID, 2><<<dim3(DIM / 128, N_TOK / 128), 256, 0, stream>>>(
            Hb, w2b + (size_t)e * DIM * HID, b2 + (size_t)e * DIM, nullptr, out, cw, e);
    }
  }
}